// Round 1
// baseline (7824.332 us; speedup 1.0000x reference)
//
#include <hip/hip_runtime.h>
#include <math.h>

#define NTOK 512
#define CD 768
#define NHD 8
#define HDIM 96
#define NLAYER 12
#define NEXP 8
#define DFFD 3072
#define TSEQ 64
#define NVOCAB 99
#define LN_EPS 1e-5f

#define BM 64
#define BN 64
#define BK 16

__device__ __forceinline__ float gelu_exact(float x) {
  return 0.5f * x * (1.0f + erff(x * 0.70710678118654752440f));
}

// ---------------- embedding ----------------
__global__ __launch_bounds__(256) void embed_kernel(
    const int* __restrict__ idx, const float* __restrict__ tok,
    const float* __restrict__ pos, float* __restrict__ x)
{
  const int t = blockIdx.x;
  const int id = idx[t];
  const int p = t & (TSEQ - 1);
  for (int c = threadIdx.x; c < CD; c += 256)
    x[(size_t)t * CD + c] = tok[(size_t)id * CD + c] + pos[(size_t)p * CD + c];
}

// ---------------- generic GEMM: C = A[M,K] * B[N,K]^T (+bias)(+res) ----------------
// blockIdx.z selects B0/B1/B2 and offsets C by z*M*N (used for fused QKV).
__global__ __launch_bounds__(256) void gemm_kernel(
    const float* __restrict__ A,
    const float* __restrict__ B0, const float* __restrict__ B1, const float* __restrict__ B2,
    const float* __restrict__ bias, const float* __restrict__ res,
    float* __restrict__ Cb, int M, int N, int K)
{
  const float* B = (blockIdx.z == 0) ? B0 : ((blockIdx.z == 1) ? B1 : B2);
  float* C = Cb + (size_t)blockIdx.z * (size_t)M * N;
  const int n0 = blockIdx.x * BN;
  const int m0 = blockIdx.y * BM;
  __shared__ __align__(16) float As[BK][BM];
  __shared__ __align__(16) float Bs[BK][BN];
  const int tid = threadIdx.x;
  const int lr = tid >> 2;            // tile row for loads (0..63)
  const int lc = (tid & 3) << 2;      // k-offset for float4 load (0,4,8,12)
  const int tm = (tid >> 4) << 2;     // micro-tile row base
  const int tn = (tid & 15) << 2;     // micro-tile col base
  float acc[4][4] = {{0.f, 0.f, 0.f, 0.f}, {0.f, 0.f, 0.f, 0.f},
                     {0.f, 0.f, 0.f, 0.f}, {0.f, 0.f, 0.f, 0.f}};
  for (int kt = 0; kt < K; kt += BK) {
    float4 av = make_float4(0.f, 0.f, 0.f, 0.f);
    float4 bv = make_float4(0.f, 0.f, 0.f, 0.f);
    const int gm = m0 + lr;
    if (gm < M) av = *(const float4*)(A + (size_t)gm * K + kt + lc);
    const int gn = n0 + lr;
    if (gn < N) bv = *(const float4*)(B + (size_t)gn * K + kt + lc);
    As[lc + 0][lr] = av.x; As[lc + 1][lr] = av.y; As[lc + 2][lr] = av.z; As[lc + 3][lr] = av.w;
    Bs[lc + 0][lr] = bv.x; Bs[lc + 1][lr] = bv.y; Bs[lc + 2][lr] = bv.z; Bs[lc + 3][lr] = bv.w;
    __syncthreads();
#pragma unroll
    for (int k = 0; k < BK; ++k) {
      const float4 a = *(const float4*)(&As[k][tm]);
      const float4 b = *(const float4*)(&Bs[k][tn]);
      const float ar[4] = {a.x, a.y, a.z, a.w};
      const float br[4] = {b.x, b.y, b.z, b.w};
#pragma unroll
      for (int i = 0; i < 4; ++i)
#pragma unroll
        for (int j = 0; j < 4; ++j)
          acc[i][j] = fmaf(ar[i], br[j], acc[i][j]);
    }
    __syncthreads();
  }
#pragma unroll
  for (int i = 0; i < 4; ++i) {
    const int gm = m0 + tm + i;
    if (gm >= M) continue;
#pragma unroll
    for (int j = 0; j < 4; ++j) {
      const int gn = n0 + tn + j;
      if (gn >= N) continue;
      float v = acc[i][j];
      if (bias) v += bias[gn];
      if (res) v += res[(size_t)gm * N + gn];
      C[(size_t)gm * N + gn] = v;
    }
  }
}

// ---------------- attention (one block per (b,h)) ----------------
__global__ __launch_bounds__(256) void attn_kernel(
    const float* __restrict__ qkv, float* __restrict__ out)
{
  const int b = blockIdx.x >> 3;
  const int h = blockIdx.x & 7;
  __shared__ float Ks[TSEQ][HDIM];
  __shared__ float Ss[TSEQ][TSEQ + 1];
  const size_t base = (size_t)b * TSEQ * CD + (size_t)h * HDIM;
  const float* q = qkv + base;
  const float* k = qkv + (size_t)NTOK * CD + base;
  const float* v = qkv + 2 * (size_t)NTOK * CD + base;
  const int tid = threadIdx.x;
  for (int i = tid; i < TSEQ * HDIM; i += 256) {
    const int t = i / HDIM, d = i - t * HDIM;
    Ks[t][d] = k[(size_t)t * CD + d];
  }
  __syncthreads();
  const int r = tid >> 2, p = tid & 3;
  const float scale = 0.10206207261596577f;  // 96^-0.5
  float sacc[16];
#pragma unroll
  for (int jj = 0; jj < 16; ++jj) sacc[jj] = 0.f;
  for (int d = 0; d < HDIM; ++d) {
    const float qd = q[(size_t)r * CD + d];
#pragma unroll
    for (int jj = 0; jj < 16; ++jj) sacc[jj] += qd * Ks[p * 16 + jj][d];
  }
#pragma unroll
  for (int jj = 0; jj < 16; ++jj) {
    const int j = p * 16 + jj;
    Ss[r][j] = (j <= r) ? sacc[jj] * scale : -1e30f;
  }
  __syncthreads();
  if (tid < TSEQ) {
    float mx = -1e30f;
    for (int j = 0; j <= tid; ++j) mx = fmaxf(mx, Ss[tid][j]);
    float sum = 0.f;
    for (int j = 0; j <= tid; ++j) { const float e = expf(Ss[tid][j] - mx); Ss[tid][j] = e; sum += e; }
    const float inv = 1.f / sum;
    for (int j = 0; j <= tid; ++j) Ss[tid][j] *= inv;
  }
  __syncthreads();
  float oacc[24];
#pragma unroll
  for (int dd = 0; dd < 24; ++dd) oacc[dd] = 0.f;
  for (int j = 0; j <= r; ++j) {
    const float pj = Ss[r][j];
    const float* vr = v + (size_t)j * CD + p * 24;
#pragma unroll
    for (int dd = 0; dd < 24; ++dd) oacc[dd] += pj * vr[dd];
  }
  float* orow = out + (size_t)(b * TSEQ + r) * CD + (size_t)h * HDIM + p * 24;
#pragma unroll
  for (int dd = 0; dd < 24; ++dd) orow[dd] = oacc[dd];
}

// ---------------- layernorm: out = LN(a) (one wave per token) ----------------
__global__ __launch_bounds__(256) void ln_kernel(
    const float* __restrict__ a, const float* __restrict__ w,
    const float* __restrict__ b, float* __restrict__ out)
{
  const int t = blockIdx.x * 4 + (threadIdx.x >> 6);
  const int lane = threadIdx.x & 63;
  const float* ar = a + (size_t)t * CD;
  float v[12];
  float s = 0.f, s2 = 0.f;
#pragma unroll
  for (int i = 0; i < 12; ++i) {
    v[i] = ar[lane + i * 64];
    s += v[i];
    s2 += v[i] * v[i];
  }
  for (int o = 32; o > 0; o >>= 1) { s += __shfl_down(s, o); s2 += __shfl_down(s2, o); }
  s = __shfl(s, 0); s2 = __shfl(s2, 0);
  const float mean = s * (1.0f / CD);
  const float var = s2 * (1.0f / CD) - mean * mean;
  const float rstd = 1.0f / sqrtf(var + LN_EPS);
  float* orow = out + (size_t)t * CD;
#pragma unroll
  for (int i = 0; i < 12; ++i) {
    const int c = lane + i * 64;
    orow[c] = (v[i] - mean) * rstd * w[c] + b[c];
  }
}

// ---------------- LN2: out = LN(x + Y2[slot0] + Y2[slot1]) ----------------
__global__ __launch_bounds__(256) void ln2_moe_kernel(
    const float* __restrict__ x, const float* __restrict__ Y2,
    const int* __restrict__ slot_of_tok, const float* __restrict__ w,
    const float* __restrict__ b, float* __restrict__ out)
{
  const int t = blockIdx.x * 4 + (threadIdx.x >> 6);
  const int lane = threadIdx.x & 63;
  const int s0 = slot_of_tok[2 * t];
  const int s1 = slot_of_tok[2 * t + 1];
  const float* xr = x + (size_t)t * CD;
  const float* y0 = Y2 + (size_t)s0 * CD;
  const float* y1 = Y2 + (size_t)s1 * CD;
  float v[12];
  float s = 0.f, s2 = 0.f;
#pragma unroll
  for (int i = 0; i < 12; ++i) {
    const int c = lane + i * 64;
    v[i] = xr[c] + y0[c] + y1[c];
    s += v[i];
    s2 += v[i] * v[i];
  }
  for (int o = 32; o > 0; o >>= 1) { s += __shfl_down(s, o); s2 += __shfl_down(s2, o); }
  s = __shfl(s, 0); s2 = __shfl(s2, 0);
  const float mean = s * (1.0f / CD);
  const float var = s2 * (1.0f / CD) - mean * mean;
  const float rstd = 1.0f / sqrtf(var + LN_EPS);
  float* orow = out + (size_t)t * CD;
#pragma unroll
  for (int i = 0; i < 12; ++i) {
    const int c = lane + i * 64;
    orow[c] = (v[i] - mean) * rstd * w[c] + b[c];
  }
}

// ---------------- gate: softmax over 8 logits, top-2, renorm ----------------
__global__ __launch_bounds__(256) void gate_kernel(
    const float* __restrict__ x, const float* __restrict__ gw,
    const float* __restrict__ gb, int* __restrict__ e_sel, float* __restrict__ p_sel)
{
  const int t = blockIdx.x * 4 + (threadIdx.x >> 6);
  const int lane = threadIdx.x & 63;
  const float* xr = x + (size_t)t * CD;
  float xs[12];
#pragma unroll
  for (int i = 0; i < 12; ++i) xs[i] = xr[lane + i * 64];
  float logits[NEXP];
#pragma unroll
  for (int e = 0; e < NEXP; ++e) {
    const float* g = gw + (size_t)e * CD;
    float s = 0.f;
#pragma unroll
    for (int i = 0; i < 12; ++i) s += xs[i] * g[lane + i * 64];
    for (int o = 32; o > 0; o >>= 1) s += __shfl_xor(s, o);
    logits[e] = s + gb[e];
  }
  if (lane == 0) {
    float mx = logits[0];
    for (int e = 1; e < NEXP; ++e) mx = fmaxf(mx, logits[e]);
    float pr[NEXP];
    float sum = 0.f;
    for (int e = 0; e < NEXP; ++e) { pr[e] = expf(logits[e] - mx); sum += pr[e]; }
    (void)sum;  // renormalized top-2 of softmax == renormalized top-2 of exps
    int i0 = 0;
    for (int e = 1; e < NEXP; ++e) if (pr[e] > pr[i0]) i0 = e;       // ties -> lowest idx (matches top_k)
    int i1 = (i0 == 0) ? 1 : 0;
    for (int e = 0; e < NEXP; ++e) if (e != i0 && pr[e] > pr[i1]) i1 = e;
    const float p0 = pr[i0], p1 = pr[i1];
    const float inv = 1.f / (p0 + p1);
    e_sel[2 * t] = i0; e_sel[2 * t + 1] = i1;
    p_sel[2 * t] = p0 * inv; p_sel[2 * t + 1] = p1 * inv;
  }
}

// ---------------- route: build per-expert slot lists (single block) ----------------
__global__ __launch_bounds__(256) void route_kernel(
    const int* __restrict__ e_sel, const float* __restrict__ p_sel,
    int* __restrict__ counts, int* __restrict__ offsets,
    int* __restrict__ tok_of_slot, float* __restrict__ prob_of_slot,
    int* __restrict__ slot_of_tok)
{
  __shared__ int cnt[NEXP], pos[NEXP], offs[NEXP];
  const int tid = threadIdx.x;
  if (tid < NEXP) { cnt[tid] = 0; pos[tid] = 0; }
  __syncthreads();
  for (int a = tid; a < 2 * NTOK; a += 256) atomicAdd(&cnt[e_sel[a]], 1);
  __syncthreads();
  if (tid == 0) {
    int o = 0;
    for (int e = 0; e < NEXP; ++e) { offs[e] = o; o += cnt[e]; }
  }
  __syncthreads();
  for (int a = tid; a < 2 * NTOK; a += 256) {
    const int e = e_sel[a];
    const int p = atomicAdd(&pos[e], 1);
    const int slot = offs[e] + p;
    tok_of_slot[slot] = a >> 1;
    prob_of_slot[slot] = p_sel[a];
    slot_of_tok[a] = slot;
  }
  if (tid < NEXP) { counts[tid] = cnt[tid]; offsets[tid] = offs[tid]; }
}

// ---------------- MoE FFN1: H = gelu(Xg * W1[e]^T + b1[e]) (gathered rows) ----------------
__global__ __launch_bounds__(256) void moe1_kernel(
    const float* __restrict__ X, const float* __restrict__ w1,
    const float* __restrict__ b1, const int* __restrict__ counts,
    const int* __restrict__ offsets, const int* __restrict__ tok_of_slot,
    float* __restrict__ H)
{
  const int e = blockIdx.z;
  const int cnt = counts[e];
  const int s0 = blockIdx.y * BM;
  if (s0 >= cnt) return;
  const int off = offsets[e];
  const int n0 = blockIdx.x * BN;
  const float* B = w1 + (size_t)e * DFFD * CD;
  __shared__ __align__(16) float As[BK][BM];
  __shared__ __align__(16) float Bs[BK][BN];
  __shared__ int rows[BM];
  const int tid = threadIdx.x;
  if (tid < BM) rows[tid] = (s0 + tid < cnt) ? tok_of_slot[off + s0 + tid] : 0;
  __syncthreads();
  const int lr = tid >> 2, lc = (tid & 3) << 2;
  const int tm = (tid >> 4) << 2, tn = (tid & 15) << 2;
  const int arow = rows[lr];
  float acc[4][4] = {{0.f, 0.f, 0.f, 0.f}, {0.f, 0.f, 0.f, 0.f},
                     {0.f, 0.f, 0.f, 0.f}, {0.f, 0.f, 0.f, 0.f}};
  for (int kt = 0; kt < CD; kt += BK) {
    const float4 av = *(const float4*)(X + (size_t)arow * CD + kt + lc);
    const float4 bv = *(const float4*)(B + (size_t)(n0 + lr) * CD + kt + lc);
    As[lc + 0][lr] = av.x; As[lc + 1][lr] = av.y; As[lc + 2][lr] = av.z; As[lc + 3][lr] = av.w;
    Bs[lc + 0][lr] = bv.x; Bs[lc + 1][lr] = bv.y; Bs[lc + 2][lr] = bv.z; Bs[lc + 3][lr] = bv.w;
    __syncthreads();
#pragma unroll
    for (int k = 0; k < BK; ++k) {
      const float4 a = *(const float4*)(&As[k][tm]);
      const float4 b = *(const float4*)(&Bs[k][tn]);
      const float ar[4] = {a.x, a.y, a.z, a.w};
      const float br[4] = {b.x, b.y, b.z, b.w};
#pragma unroll
      for (int i = 0; i < 4; ++i)
#pragma unroll
        for (int j = 0; j < 4; ++j)
          acc[i][j] = fmaf(ar[i], br[j], acc[i][j]);
    }
    __syncthreads();
  }
  const float* b1e = b1 + (size_t)e * DFFD;
#pragma unroll
  for (int i = 0; i < 4; ++i) {
    const int sm = s0 + tm + i;
    if (sm >= cnt) continue;
#pragma unroll
    for (int j = 0; j < 4; ++j) {
      const int gn = n0 + tn + j;
      H[(size_t)(off + sm) * DFFD + gn] = gelu_exact(acc[i][j] + b1e[gn]);
    }
  }
}

// ---------------- MoE FFN2: Y2[slot] = p * (H * W2[e]^T + b2[e]) ----------------
__global__ __launch_bounds__(256) void moe2_kernel(
    const float* __restrict__ H, const float* __restrict__ w2,
    const float* __restrict__ b2, const int* __restrict__ counts,
    const int* __restrict__ offsets, const float* __restrict__ prob_of_slot,
    float* __restrict__ Y2)
{
  const int e = blockIdx.z;
  const int cnt = counts[e];
  const int s0 = blockIdx.y * BM;
  if (s0 >= cnt) return;
  const int off = offsets[e];
  const int n0 = blockIdx.x * BN;
  const float* A = H + (size_t)off * DFFD;
  const float* B = w2 + (size_t)e * CD * DFFD;
  __shared__ __align__(16) float As[BK][BM];
  __shared__ __align__(16) float Bs[BK][BN];
  const int tid = threadIdx.x;
  const int lr = tid >> 2, lc = (tid & 3) << 2;
  const int tm = (tid >> 4) << 2, tn = (tid & 15) << 2;
  const int ar_ = (s0 + lr < cnt) ? (s0 + lr) : 0;  // clamp: invalid rows discarded at store
  float acc[4][4] = {{0.f, 0.f, 0.f, 0.f}, {0.f, 0.f, 0.f, 0.f},
                     {0.f, 0.f, 0.f, 0.f}, {0.f, 0.f, 0.f, 0.f}};
  for (int kt = 0; kt < DFFD; kt += BK) {
    const float4 av = *(const float4*)(A + (size_t)ar_ * DFFD + kt + lc);
    const float4 bv = *(const float4*)(B + (size_t)(n0 + lr) * DFFD + kt + lc);
    As[lc + 0][lr] = av.x; As[lc + 1][lr] = av.y; As[lc + 2][lr] = av.z; As[lc + 3][lr] = av.w;
    Bs[lc + 0][lr] = bv.x; Bs[lc + 1][lr] = bv.y; Bs[lc + 2][lr] = bv.z; Bs[lc + 3][lr] = bv.w;
    __syncthreads();
#pragma unroll
    for (int k = 0; k < BK; ++k) {
      const float4 a = *(const float4*)(&As[k][tm]);
      const float4 b = *(const float4*)(&Bs[k][tn]);
      const float ar[4] = {a.x, a.y, a.z, a.w};
      const float br[4] = {b.x, b.y, b.z, b.w};
#pragma unroll
      for (int i = 0; i < 4; ++i)
#pragma unroll
        for (int j = 0; j < 4; ++j)
          acc[i][j] = fmaf(ar[i], br[j], acc[i][j]);
    }
    __syncthreads();
  }
  const float* b2e = b2 + (size_t)e * CD;
#pragma unroll
  for (int i = 0; i < 4; ++i) {
    const int sm = s0 + tm + i;
    if (sm >= cnt) continue;
    const int slot = off + sm;
    const float pp = prob_of_slot[slot];
#pragma unroll
    for (int j = 0; j < 4; ++j) {
      const int gn = n0 + tn + j;
      Y2[(size_t)slot * CD + gn] = pp * (acc[i][j] + b2e[gn]);
    }
  }
}

extern "C" void kernel_launch(void* const* d_in, const int* in_sizes, int n_in,
                              void* d_out, int out_size, void* d_ws, size_t ws_size,
                              hipStream_t stream)
{
  (void)in_sizes; (void)n_in; (void)out_size; (void)ws_size;
  const int*   idx     = (const int*)  d_in[0];
  const float* tok_emb = (const float*)d_in[1];
  const float* pos_emb = (const float*)d_in[2];
  const float* wq      = (const float*)d_in[3];
  const float* wk      = (const float*)d_in[4];
  const float* wv      = (const float*)d_in[5];
  const float* wproj   = (const float*)d_in[6];
  const float* bproj   = (const float*)d_in[7];
  const float* gate_w  = (const float*)d_in[8];
  const float* gate_b  = (const float*)d_in[9];
  const float* w1      = (const float*)d_in[10];
  const float* b1      = (const float*)d_in[11];
  const float* w2      = (const float*)d_in[12];
  const float* b2      = (const float*)d_in[13];
  const float* ln1_w   = (const float*)d_in[14];
  const float* ln1_b   = (const float*)d_in[15];
  const float* ln2_w   = (const float*)d_in[16];
  const float* ln2_b   = (const float*)d_in[17];
  const float* lnf_w   = (const float*)d_in[18];
  const float* lnf_b   = (const float*)d_in[19];
  const float* lm_w    = (const float*)d_in[20];
  const float* lm_b    = (const float*)d_in[21];

  float* ws = (float*)d_ws;
  const size_t XSZ = (size_t)NTOK * CD;  // 393216
  float* X      = ws;                    // persistent activations
  float* XF     = X + XSZ;
  float* region = XF + XSZ;              // overlay: {QKV,ATT,XRES} then {H,Y2}
  float* QKV  = region;                  // 3*XSZ
  float* ATT  = region + 3 * XSZ;        // XSZ
  float* XRES = region + 4 * XSZ;        // XSZ
  float* H    = region;                  // 1024*3072 = 8*XSZ (reuses dead QKV/ATT/XRES)
  float* Y2   = region + (size_t)1024 * DFFD;  // 1024*768 = 2*XSZ
  float* p_sel        = region + 10 * XSZ;
  float* prob_of_slot = p_sel + 1024;
  int*   e_sel        = (int*)(prob_of_slot + 1024);
  int*   tok_of_slot  = e_sel + 1024;
  int*   slot_of_tok  = tok_of_slot + 1024;
  int*   counts       = slot_of_tok + 1024;
  int*   offsets      = counts + NEXP;

  embed_kernel<<<NTOK, 256, 0, stream>>>(idx, tok_emb, pos_emb, X);

  for (int l = 0; l < NLAYER; ++l) {
    const float* wq_l = wq + (size_t)l * CD * CD;
    const float* wk_l = wk + (size_t)l * CD * CD;
    const float* wv_l = wv + (size_t)l * CD * CD;
    const float* wp_l = wproj + (size_t)l * CD * CD;
    const float* bp_l = bproj + (size_t)l * CD;
    const float* gw_l = gate_w + (size_t)l * NEXP * CD;
    const float* gb_l = gate_b + (size_t)l * NEXP;
    const float* w1_l = w1 + (size_t)l * NEXP * DFFD * CD;
    const float* b1_l = b1 + (size_t)l * NEXP * DFFD;
    const float* w2_l = w2 + (size_t)l * NEXP * CD * DFFD;
    const float* b2_l = b2 + (size_t)l * NEXP * CD;

    // QKV: one launch, z selects weight
    gemm_kernel<<<dim3(CD / BN, NTOK / BM, 3), 256, 0, stream>>>(
        X, wq_l, wk_l, wv_l, nullptr, nullptr, QKV, NTOK, CD, CD);
    attn_kernel<<<64, 256, 0, stream>>>(QKV, ATT);
    // proj + bias + residual(X)
    gemm_kernel<<<dim3(CD / BN, NTOK / BM, 1), 256, 0, stream>>>(
        ATT, wp_l, wp_l, wp_l, bp_l, X, XRES, NTOK, CD, CD);
    ln_kernel<<<NTOK / 4, 256, 0, stream>>>(XRES, ln1_w + (size_t)l * CD, ln1_b + (size_t)l * CD, X);
    gate_kernel<<<NTOK / 4, 256, 0, stream>>>(X, gw_l, gb_l, e_sel, p_sel);
    route_kernel<<<1, 256, 0, stream>>>(e_sel, p_sel, counts, offsets,
                                        tok_of_slot, prob_of_slot, slot_of_tok);
    moe1_kernel<<<dim3(DFFD / BN, 8, NEXP), 256, 0, stream>>>(
        X, w1_l, b1_l, counts, offsets, tok_of_slot, H);
    moe2_kernel<<<dim3(CD / BN, 8, NEXP), 256, 0, stream>>>(
        H, w2_l, b2_l, counts, offsets, prob_of_slot, Y2);
    ln2_moe_kernel<<<NTOK / 4, 256, 0, stream>>>(X, Y2, slot_of_tok,
                                                 ln2_w + (size_t)l * CD, ln2_b + (size_t)l * CD, X);
  }

  ln_kernel<<<NTOK / 4, 256, 0, stream>>>(X, lnf_w, lnf_b, XF);
  gemm_kernel<<<dim3((NVOCAB + BN - 1) / BN, NTOK / BM, 1), 256, 0, stream>>>(
      XF, lm_w, lm_w, lm_w, lm_b, nullptr, (float*)d_out, NTOK, NVOCAB, CD);
}